// Round 5
// baseline (286.839 us; speedup 1.0000x reference)
//
#include <hip/hip_runtime.h>
#include <stdint.h>

#define BB     64
#define CC     12
#define LL     2048
#define KERNSZ 9
#define KK     8     // kernels per group
#define GG     32    // groups per branch (_G)
#define NPER   6
#define NDIL   8
#define PAD    512   // max halo = 4*d, d<=128
#define MAIN   2048
#define BUFSZ  (PAD + MAIN + PAD)   // 3072 floats = 12 KB per wave
#define WPB    4                    // waves per block -> 48 KB LDS -> 3 blocks/CU

typedef float f2 __attribute__((ext_vector_type(2)));

// acc.{lo,hi} += t.LO * w.{lo,hi}  (broadcast low half of src0)
__device__ __forceinline__ void pk_fma_lo(f2& acc, const f2& t, uint64_t wpair) {
    asm("v_pk_fma_f32 %0, %1, %2, %0 op_sel:[0,0,0] op_sel_hi:[0,1,1]"
        : "+v"(acc) : "v"(t), "s"(wpair));
}
// acc.{lo,hi} += t.HI * w.{lo,hi}  (broadcast high half of src0)
__device__ __forceinline__ void pk_fma_hi(f2& acc, const f2& t, uint64_t wpair) {
    asm("v_pk_fma_f32 %0, %1, %2, %0 op_sel:[1,0,0] op_sel_hi:[1,1,1]"
        : "+v"(acc) : "v"(t), "s"(wpair));
}
__device__ __forceinline__ f2 pk_mul_lo(const f2& t, uint64_t wpair) {
    f2 d;
    asm("v_pk_mul_f32 %0, %1, %2 op_sel:[0,0] op_sel_hi:[0,1]"
        : "=v"(d) : "v"(t), "s"(wpair));
    return d;
}

// Phase 2, specialized on compile-time dilation D (tap offsets are immediates).
template <int D>
__device__ __forceinline__ void run_phase2(
    const float* __restrict__ sel, int lane, int dif,
    const uint64_t (&wp)[4][KERNSZ], f2 (&accM)[4], uint32_t (&accN)[KK])
{
    const float NANF = __uint_as_float(0x7fc00000u);

    for (int q = 0; q < 32; ++q) {
        const int pos = q * 64 + lane;
        const float* p = sel + pos - 4 * D;   // pads make all 9 taps valid

        // taps staged as pairs -> ds_read2_b32 (two taps per LDS instruction)
        f2 tp[4];
        #pragma unroll
        for (int m = 0; m < 4; ++m) {
            tp[m].x = p[(2 * m)     * D];
            tp[m].y = p[(2 * m + 1) * D];
        }
        f2 t8; t8.x = p[8 * D];               // .y unused (op_sel ignores it)

        f2 v2[4];                              // (v0,v1)(v2,v3)(v4,v5)(v6,v7)
        #pragma unroll
        for (int c = 0; c < 4; ++c)
            v2[c] = pk_mul_lo(tp[0], wp[c][0]);
        #pragma unroll
        for (int c = 0; c < 4; ++c)
            pk_fma_hi(v2[c], tp[0], wp[c][1]);
        #pragma unroll
        for (int m = 1; m < 4; ++m) {
            #pragma unroll
            for (int c = 0; c < 4; ++c)
                pk_fma_lo(v2[c], tp[m], wp[c][2 * m]);
            #pragma unroll
            for (int c = 0; c < 4; ++c)
                pk_fma_hi(v2[c], tp[m], wp[c][2 * m + 1]);
        }
        #pragma unroll
        for (int c = 0; c < 4; ++c)
            pk_fma_lo(v2[c], t8, wp[c][8]);

        // balanced max/min trees on register halves (v_max3/v_min3)
        float ma = fmaxf(fmaxf(v2[0].x, v2[0].y), fmaxf(v2[1].x, v2[1].y));
        float mb = fmaxf(fmaxf(v2[2].x, v2[2].y), fmaxf(v2[3].x, v2[3].y));
        float mv = fmaxf(ma, mb);
        float na = fminf(fminf(v2[0].x, v2[0].y), fminf(v2[1].x, v2[1].y));
        float nb = fminf(fminf(v2[2].x, v2[2].y), fminf(v2[3].x, v2[3].y));
        float nv = fminf(na, nb);

        // only invalid output position: pos==2047 on diff branch.
        // NaN never compares equal -> contributes nothing below.
        if (dif && q == 31) {
            if (lane == 63) { mv = NANF; nv = NANF; }
        }

        #pragma unroll
        for (int c = 0; c < 4; ++c) {
            f2 am;
            am.x = (v2[c].x == mv) ? v2[c].x : 0.0f;  // exact: mv bit-equals winner
            am.y = (v2[c].y == mv) ? v2[c].y : 0.0f;
            accM[c] += am;                             // v_pk_add_f32
            accN[2 * c]     += (v2[c].x == nv) ? 1u : 0u;  // v_cmp + v_addc
            accN[2 * c + 1] += (v2[c].y == nv) ? 1u : 0u;
        }
    }
}

__global__ __launch_bounds__(256) void hydra_kernel(
    const float* __restrict__ X,    // [B, C, L]
    const float* __restrict__ W,    // [NDIL, 2, KK*GG, 1, KERNSZ]
    const int*   __restrict__ I,    // [NDIL, 2, GG, NPER]
    float*       __restrict__ out)  // [B, 8192]
{
    __shared__ float lds[WPB][BUFSZ];

    const int tid  = threadIdx.x;
    const int wave = tid >> 6;
    const int lane = tid & 63;
    const int wid  = blockIdx.x * WPB + wave;   // 0..32767
    // task decode: wid = b*512 + di*64 + dif*32 + g
    const int b   = wid >> 9;
    const int r   = wid & 511;
    const int di  = r >> 6;
    const int r2  = r & 63;
    const int dif = r2 >> 5;
    const int g   = r2 & 31;

    float* buf = lds[wave];
    float* sel = buf + PAD;

    // ---- zero halo pads ----
    #pragma unroll
    for (int i = 0; i < PAD; i += 128) {
        *(f2*)(buf + i + 2 * lane)              = f2{0.f, 0.f};
        *(f2*)(buf + PAD + MAIN + i + 2 * lane) = f2{0.f, 0.f};
    }

    // ---- phase 1: channel-subset sum S into sel[0..2047] (f2 loads) ----
    const int* Ig = I + ((size_t)((di * 2 + dif) * GG + g)) * NPER;
    const float* xb = X + (size_t)b * CC * LL;
    const float* c0 = xb + Ig[0] * LL;
    const float* c1 = xb + Ig[1] * LL;
    const float* c2 = xb + Ig[2] * LL;
    const float* c3 = xb + Ig[3] * LL;
    const float* c4 = xb + Ig[4] * LL;
    const float* c5 = xb + Ig[5] * LL;

    #pragma unroll 1
    for (int q = 0; q < 16; ++q) {
        int pp = (q * 64 + lane) * 2;
        f2 s = *(const f2*)(c0 + pp) + *(const f2*)(c1 + pp)
             + *(const f2*)(c2 + pp) + *(const f2*)(c3 + pp)
             + *(const f2*)(c4 + pp) + *(const f2*)(c5 + pp);
        *(f2*)(sel + pp) = s;
    }

    if (dif) {
        // in-place wave-synchronous diff (validated R1/R3): reads of pos,pos+1
        // issue before the write; lane63's pos+1 read targets data rewritten
        // only at iteration q+1. sel[2048] is the zeroed right pad.
        for (int q = 0; q < 32; ++q) {
            int pos = q * 64 + lane;
            float a  = sel[pos];
            float an = sel[pos + 1];
            float v  = (pos == (LL - 1)) ? 0.0f : (an - a);
            sel[pos] = v;
        }
    }

    // ---- weights: wave-uniform scalar loads, packed into SGPR pairs ----
    const float* Wg = W + (size_t)((di * 2 + dif) * (KK * GG) + g * KK) * KERNSZ;
    uint64_t wp[4][KERNSZ];   // wp[c][j] = (w[2c][j], w[2c+1][j])
    #pragma unroll
    for (int c = 0; c < 4; ++c)
        #pragma unroll
        for (int j = 0; j < KERNSZ; ++j) {
            uint32_t lo = __float_as_uint(Wg[(2 * c)     * KERNSZ + j]);
            uint32_t hi = __float_as_uint(Wg[(2 * c + 1) * KERNSZ + j]);
            wp[c][j] = (uint64_t)lo | ((uint64_t)hi << 32);
        }

    f2       accM[4];
    uint32_t accN[KK];
    #pragma unroll
    for (int c = 0; c < 4; ++c) accM[c] = f2{0.f, 0.f};
    #pragma unroll
    for (int k = 0; k < KK; ++k) accN[k] = 0u;

    switch (di) {   // block-uniform branch
        case 0: run_phase2<1>  (sel, lane, dif, wp, accM, accN); break;
        case 1: run_phase2<2>  (sel, lane, dif, wp, accM, accN); break;
        case 2: run_phase2<4>  (sel, lane, dif, wp, accM, accN); break;
        case 3: run_phase2<8>  (sel, lane, dif, wp, accM, accN); break;
        case 4: run_phase2<16> (sel, lane, dif, wp, accM, accN); break;
        case 5: run_phase2<32> (sel, lane, dif, wp, accM, accN); break;
        case 6: run_phase2<64> (sel, lane, dif, wp, accM, accN); break;
        default: run_phase2<128>(sel, lane, dif, wp, accM, accN); break;
    }

    // ---- wave butterfly reduction of the 16 accumulators ----
    float* o = out + (size_t)b * 8192 + (size_t)((di * 2 + dif) * 2) * 256 + g * KK;
    #pragma unroll
    for (int k = 0; k < KK; ++k) {
        float a = (k & 1) ? accM[k >> 1].y : accM[k >> 1].x;
        unsigned c = accN[k];
        #pragma unroll
        for (int off = 32; off > 0; off >>= 1) {
            a += __shfl_xor(a, off, 64);
            c += __shfl_xor(c, off, 64);
        }
        if (lane == 0) {
            o[k]       = a;          // count_max block (which=0)
            o[256 + k] = (float)c;   // count_min block (which=1)
        }
    }
}

extern "C" void kernel_launch(void* const* d_in, const int* in_sizes, int n_in,
                              void* d_out, int out_size, void* d_ws, size_t ws_size,
                              hipStream_t stream) {
    const float* X = (const float*)d_in[0];
    const float* W = (const float*)d_in[1];
    const int*   I = (const int*)d_in[2];
    float* out = (float*)d_out;

    const int total_waves = BB * NDIL * 2 * GG;       // 32768
    const int blocks = total_waves / WPB;             // 8192
    hydra_kernel<<<blocks, 256, 0, stream>>>(X, W, I, out);
}